// Round 7
// baseline (126.789 us; speedup 1.0000x reference)
//
#include <hip/hip_runtime.h>
#include <hip/hip_bf16.h>

#define L_N 64
#define T_N 8192
#define K_N 128
#define N_N 128
#define BM  128
#define NT  2      // tiles per block (R6-verified: keeps 2048 blocks of slack)

typedef __attribute__((ext_vector_type(8))) short short8;   // 8 bf16 = 4 VGPR
typedef __attribute__((ext_vector_type(4))) float f32x4;    // MFMA acc

__device__ __forceinline__ unsigned short f2bf(float f) {
    union { float f; unsigned u; } c; c.f = f;
    return (unsigned short)((c.u + 0x7fffu + ((c.u >> 16) & 1u)) >> 16);  // RNE
}

// Prepass: w [L][K][N] fp32 -> pre-fragmented bf16  wf[l][ni][kk][lane][j]
//   element (l,ni,kk,lane,j) = w[l][ kk*32 + (lane>>4)*8 + j ][ ni*16 + (lane&15) ]
// (verified R2-R6). Main kernel stages wf[l] to LDS as a LINEAR copy; fragment
// reads are lane-consecutive 16B -> conflict-free by construction.
__global__ __launch_bounds__(256) void wfrag_kernel(const float* __restrict__ w,
                                                    unsigned short* __restrict__ wf) {
    __shared__ float lds[K_N * 129];            // +1 pad, 66 KB
    const int l = blockIdx.x;
    const float* wl = w + (size_t)l * (K_N * N_N);
    const int tid = threadIdx.x;
    #pragma unroll
    for (int i = 0; i < 16; ++i) {
        int f = i * 256 + tid;                  // float4 idx, coalesced
        float4 v = ((const float4*)wl)[f];
        int k = f >> 5, n = (f & 31) * 4;
        lds[k * 129 + n + 0] = v.x;
        lds[k * 129 + n + 1] = v.y;
        lds[k * 129 + n + 2] = v.z;
        lds[k * 129 + n + 3] = v.w;
    }
    __syncthreads();
    unsigned short* o = wf + (size_t)l * (N_N * K_N);
    #pragma unroll
    for (int c = 0; c < 16; ++c) {
        int chunk = c * 256 + tid;              // ushort4 idx, coalesced write
        int j0   = (chunk & 1) * 4;
        int lane = (chunk >> 1) & 63;
        int kk   = (chunk >> 7) & 3;
        int ni   = chunk >> 9;
        int n  = ni * 16 + (lane & 15);
        int kb = kk * 32 + (lane >> 4) * 8 + j0;
        ushort4 ov;
        ov.x = f2bf(lds[(kb + 0) * 129 + n]);
        ov.y = f2bf(lds[(kb + 1) * 129 + n]);
        ov.z = f2bf(lds[(kb + 2) * 129 + n]);
        ov.w = f2bf(lds[(kb + 3) * 129 + n]);
        ((ushort4*)o)[chunk] = ov;
    }
}

// Main: FULLY WAVE-INDEPENDENT main loop — zero barriers after the one-time
// w-stage. Each wave owns 16 rows end-to-end: loads its own 8KB x span
// (coalesced), converts, writes its OWN 4KB LDS window (swizzled), reads its
// fragments from its own window, MFMAs vs shared read-only wsh, transposes
// through its own window, stores. 16 free-running waves/CU keep a continuous
// mixed VMEM stream (no lockstepped read/compute/store bursts).
__global__ __launch_bounds__(512, 4) void gl_kernel(const float* __restrict__ x,
                                                    const unsigned short* __restrict__ wf,
                                                    const float* __restrict__ bias,
                                                    float* __restrict__ out) {
    __shared__ __align__(16) char smem[65536];
    unsigned short* wsh = (unsigned short*)(smem + 32768);  // 32KB w fragments (read-only after stage)

    const int tid  = threadIdx.x;
    const int lane = tid & 63;
    const int wid  = tid >> 6;                  // 8 waves; wave owns rows [wid*16, wid*16+16)
    const int lr   = lane & 15;
    const int lg   = lane >> 4;

    const int bid = blockIdx.x;                 // 2048 blocks = 64 layers x 32 pairs
    const int l   = bid >> 5;
    const int sub = bid & 31;

    // stage w once (linear 32KB copy, conflict-free both sides), ONLY barrier
    const unsigned short* wl = wf + (size_t)l * (N_N * K_N);
    #pragma unroll
    for (int i = 0; i < 4; ++i) {
        int c = i * 512 + tid;
        ((short8*)wsh)[c] = ((const short8*)wl)[c];
    }

    const float* bl = bias + l * N_N;
    // wave-private pointers: this wave's 16 rows within tile 0
    const float* xw0 = x + ((size_t)l * T_N + (size_t)sub * (NT * BM) + wid * 16) * K_N;
    unsigned short* xw = (unsigned short*)(smem + wid * 4096);   // own 4KB window

    // prologue: prefetch own rows of tile 0 (8KB span, 1KB/instr coalesced)
    float4 pf[8];                               // static indices only (rule #20)
    #pragma unroll
    for (int j = 0; j < 8; ++j)
        pf[j] = ((const float4*)xw0)[j * 64 + lane];

    __syncthreads();                            // wsh visible; last barrier in kernel

    for (int it = 0; it < NT; ++it) {
        // convert pf -> own window (swizzled 8B writes, <=2-way banks)
        #pragma unroll
        for (int j = 0; j < 8; ++j) {
            int f = j * 64 + lane;              // f4 index within own 8KB span
            int row = f >> 5;                   // local row 0..15
            int kc  = (f & 31) * 4;
            union { unsigned short s[4]; unsigned long long u; } p;
            p.s[0] = f2bf(pf[j].x); p.s[1] = f2bf(pf[j].y);
            p.s[2] = f2bf(pf[j].z); p.s[3] = f2bf(pf[j].w);
            int us = (row * K_N + kc) ^ ((row & 7) << 3);
            *(unsigned long long*)&xw[us] = p.u;
        }

        // issue next tile's loads now: latency hides under MFMA+epilogue+stores
        if (it + 1 < NT) {
            const float4* nx = (const float4*)(xw0 + (size_t)(it + 1) * BM * K_N);
            #pragma unroll
            for (int j = 0; j < 8; ++j)
                pf[j] = nx[j * 64 + lane];
        }

        // MFMA: own 16 rows x 128 cols (intra-wave lgkmcnt orders write->read)
        f32x4 acc[8];
        #pragma unroll
        for (int ni = 0; ni < 8; ++ni)
            acc[ni] = (f32x4){0.f, 0.f, 0.f, 0.f};
        #pragma unroll
        for (int kk = 0; kk < 4; ++kk) {
            const short8 xb = *(const short8*)&xw[(lr * K_N + kk * 32 + lg * 8) ^ ((lr & 7) << 3)];
            #pragma unroll
            for (int ni = 0; ni < 8; ++ni) {
                const short8 wv = ((const short8*)wsh)[(ni * 4 + kk) * 64 + lane];
                acc[ni] = __builtin_amdgcn_mfma_f32_16x16x32_bf16(wv, xb, acc[ni], 0, 0, 0);
            }
        }

        // barrier-free epilogue through own window (x data dead after kk loop)
        float4* osm = (float4*)xw;              // 256 f4 = 4KB, 2 column-halves
        float4* og4 = (float4*)(out + ((size_t)l * T_N + (size_t)(sub * NT + it) * BM + wid * 16) * N_N);
        #pragma unroll
        for (int h = 0; h < 2; ++h) {           // column halves [h*64, h*64+64)
            #pragma unroll
            for (int q = 0; q < 4; ++q) {
                const int ni = h * 4 + q;
                const float4 bv = *(const float4*)(bl + ni * 16 + lg * 4);
                float4 r;
                r.x = acc[ni][0] + bv.x;
                r.y = acc[ni][1] + bv.y;
                r.z = acc[ni][2] + bv.z;
                r.w = acc[ni][3] + bv.w;
                osm[lr * 16 + ((q * 4 + lg) ^ lr)] = r;   // XOR-swizzled, row=lr
            }
            #pragma unroll
            for (int q2 = 0; q2 < 4; ++q2) {    // flat read -> 1KB/instr stores
                const int fi = q2 * 64 + lane;
                const int rr = fi >> 4, cc = fi & 15;
                const float4 v = osm[rr * 16 + (cc ^ rr)];
                og4[(size_t)rr * 32 + h * 16 + cc] = v;
            }
        }
    }
}

extern "C" void kernel_launch(void* const* d_in, const int* in_sizes, int n_in,
                              void* d_out, int out_size, void* d_ws, size_t ws_size,
                              hipStream_t stream) {
    const float* x = (const float*)d_in[0];
    const float* w = (const float*)d_in[1];
    const float* b = (const float*)d_in[2];
    float* out = (float*)d_out;
    unsigned short* wf = (unsigned short*)d_ws;   // 2 MB scratch, rewritten every call

    wfrag_kernel<<<L_N, 256, 0, stream>>>(w, wf);
    gl_kernel<<<L_N * (T_N / BM) / NT, 512, 0, stream>>>(x, wf, b, out);
}

// Round 8
// 105.797 us; speedup vs baseline: 1.1984x; 1.1984x over previous
//
#include <hip/hip_runtime.h>
#include <hip/hip_bf16.h>

#define L_N 64
#define T_N 8192
#define K_N 128
#define N_N 128
#define BM  64     // rows per block: 48KB LDS -> 3 blocks/CU = 24 waves/CU

typedef __attribute__((ext_vector_type(8))) short short8;   // 8 bf16 = 4 VGPR
typedef __attribute__((ext_vector_type(4))) float f32x4;    // MFMA acc

__device__ __forceinline__ unsigned short f2bf(float f) {
    union { float f; unsigned u; } c; c.f = f;
    return (unsigned short)((c.u + 0x7fffu + ((c.u >> 16) & 1u)) >> 16);  // RNE
}

// Prepass: w [L][K][N] fp32 -> pre-fragmented bf16  wf[l][ni][kk][lane][j]
//   element (l,ni,kk,lane,j) = w[l][ kk*32 + (lane>>4)*8 + j ][ ni*16 + (lane&15) ]
// (verified R2-R7). Main kernel stages wf[l] to LDS as a LINEAR copy; fragment
// reads are lane-consecutive 16B -> conflict-free by construction.
__global__ __launch_bounds__(256) void wfrag_kernel(const float* __restrict__ w,
                                                    unsigned short* __restrict__ wf) {
    __shared__ float lds[K_N * 129];            // +1 pad, 66 KB
    const int l = blockIdx.x;
    const float* wl = w + (size_t)l * (K_N * N_N);
    const int tid = threadIdx.x;
    #pragma unroll
    for (int i = 0; i < 16; ++i) {
        int f = i * 256 + tid;                  // float4 idx, coalesced
        float4 v = ((const float4*)wl)[f];
        int k = f >> 5, n = (f & 31) * 4;
        lds[k * 129 + n + 0] = v.x;
        lds[k * 129 + n + 1] = v.y;
        lds[k * 129 + n + 2] = v.z;
        lds[k * 129 + n + 3] = v.w;
    }
    __syncthreads();
    unsigned short* o = wf + (size_t)l * (N_N * K_N);
    #pragma unroll
    for (int c = 0; c < 16; ++c) {
        int chunk = c * 256 + tid;              // ushort4 idx, coalesced write
        int j0   = (chunk & 1) * 4;
        int lane = (chunk >> 1) & 63;
        int kk   = (chunk >> 7) & 3;
        int ni   = chunk >> 9;
        int n  = ni * 16 + (lane & 15);
        int kb = kk * 32 + (lane >> 4) * 8 + j0;
        ushort4 ov;
        ov.x = f2bf(lds[(kb + 0) * 129 + n]);
        ov.y = f2bf(lds[(kb + 1) * 129 + n]);
        ov.z = f2bf(lds[(kb + 2) * 129 + n]);
        ov.w = f2bf(lds[(kb + 3) * 129 + n]);
        ((ushort4*)o)[chunk] = ov;
    }
}

// Main: one 64-row tile per block, 512 threads, 48KB LDS -> 3 blocks/CU
// (24 waves/CU, +50% TLP vs R4). Lockstep load->barrier->MFMA->barrier->store
// phases (R4-verified memory-friendly structure). 8 waves = 4 row-strips x
// 2 col-halves; wave = 16 rows x 64 cols (acc = 16 VGPR, fits 6-wave/SIMD cap).
__global__ __launch_bounds__(512, 6) void gl_kernel(const float* __restrict__ x,
                                                    const unsigned short* __restrict__ wf,
                                                    const float* __restrict__ bias,
                                                    float* __restrict__ out) {
    __shared__ __align__(16) char smem[49152];
    unsigned short* xs  = (unsigned short*)smem;            // 16KB: 64 x-rows bf16, swizzled
    unsigned short* wsh = (unsigned short*)(smem + 16384);  // 32KB: w fragments, linear

    const int tid  = threadIdx.x;
    const int lane = tid & 63;
    const int wid  = tid >> 6;
    const int lr   = lane & 15;
    const int lg   = lane >> 4;
    const int ws   = wid >> 1;                  // row strip 0..3 (16 rows each)
    const int ch   = wid & 1;                   // column half 0..1 (64 cols each)

    const int bid  = blockIdx.x;                // 8192 blocks = 64 layers x 128 tiles
    const int l    = bid >> 7;
    const int tile = bid & 127;
    const float* xg = x + ((size_t)l * T_N + (size_t)tile * BM) * K_N;
    const unsigned short* wl = wf + (size_t)l * (N_N * K_N);

    // stage x: 64 rows fp32 (32KB) = 4 float4/thread, coalesced; swizzled bf16 writes
    #pragma unroll
    for (int i = 0; i < 4; ++i) {
        int f = i * 512 + tid;                  // float4 index, 2048 total
        const float4 v = ((const float4*)xg)[f];
        int row = f >> 5;                       // 0..63
        int kc  = (f & 31) * 4;
        union { unsigned short s[4]; unsigned long long u; } p;
        p.s[0] = f2bf(v.x); p.s[1] = f2bf(v.y); p.s[2] = f2bf(v.z); p.s[3] = f2bf(v.w);
        int us = (row * K_N + kc) ^ ((row & 7) << 3);
        *(unsigned long long*)&xs[us] = p.u;
    }
    // stage w: linear 32KB copy (2048 x 16B), conflict-free both sides
    #pragma unroll
    for (int i = 0; i < 4; ++i) {
        int c = i * 512 + tid;
        ((short8*)wsh)[c] = ((const short8*)wl)[c];
    }
    __syncthreads();

    // MFMA: wave computes 16 rows (strip ws) x 64 cols (half ch)
    f32x4 acc[4];
    #pragma unroll
    for (int q = 0; q < 4; ++q)
        acc[q] = (f32x4){0.f, 0.f, 0.f, 0.f};
    const int row = ws * 16 + lr;
    #pragma unroll
    for (int kk = 0; kk < 4; ++kk) {
        const short8 xb = *(const short8*)&xs[(row * K_N + kk * 32 + lg * 8) ^ ((row & 7) << 3)];
        #pragma unroll
        for (int q = 0; q < 4; ++q) {
            const int ni = ch * 4 + q;
            const short8 wv = ((const short8*)wsh)[(ni * 4 + kk) * 64 + lane];
            acc[q] = __builtin_amdgcn_mfma_f32_16x16x32_bf16(wv, xb, acc[q], 0, 0, 0);
        }
    }
    __syncthreads();                            // all fragment reads done; LDS reusable

    // epilogue: bias -> wave-private 4KB window transpose -> 256B-segment stores
    const float* bl = bias + l * N_N;
    float4* osm = (float4*)(smem + wid * 4096); // 16 rows x 16 f4
    #pragma unroll
    for (int q = 0; q < 4; ++q) {
        const int ni = ch * 4 + q;
        const float4 bv = *(const float4*)(bl + ni * 16 + lg * 4);
        float4 r;
        r.x = acc[q][0] + bv.x;
        r.y = acc[q][1] + bv.y;
        r.z = acc[q][2] + bv.z;
        r.w = acc[q][3] + bv.w;
        osm[lr * 16 + ((q * 4 + lg) ^ lr)] = r; // XOR-swizzled, row=lr
    }
    float4* og4 = (float4*)(out + ((size_t)l * T_N + (size_t)tile * BM + ws * 16) * N_N);
    #pragma unroll
    for (int q2 = 0; q2 < 4; ++q2) {            // 4 rows x 256B contiguous per inst
        const int fi = q2 * 64 + lane;
        const int rr = fi >> 4, cc = fi & 15;
        const float4 v = osm[rr * 16 + (cc ^ rr)];
        og4[(size_t)rr * 32 + ch * 16 + cc] = v;
    }
}

extern "C" void kernel_launch(void* const* d_in, const int* in_sizes, int n_in,
                              void* d_out, int out_size, void* d_ws, size_t ws_size,
                              hipStream_t stream) {
    const float* x = (const float*)d_in[0];
    const float* w = (const float*)d_in[1];
    const float* b = (const float*)d_in[2];
    float* out = (float*)d_out;
    unsigned short* wf = (unsigned short*)d_ws;   // 2 MB scratch, rewritten every call

    wfrag_kernel<<<L_N, 256, 0, stream>>>(w, wf);
    gl_kernel<<<L_N * (T_N / BM), 512, 0, stream>>>(x, wf, b, out);
}